// Round 3
// baseline (136.645 us; speedup 1.0000x reference)
//
#include <hip/hip_runtime.h>

#define H 1024
#define B2 2
#define LEN 8192
#define V 50000

__device__ __forceinline__ float dot4(float4 a, float4 b) {
    return a.x * b.x + a.y * b.y + a.z * b.z + a.w * b.w;
}

// ---------------------------------------------------------------------------
// K1: fused pre-work.
//   blocks 0..63    : u[h] = sum_k v[k]*attn_w[k*2048+1024+h]  (16 h per block,
//                     block-local k reduction -> no second kernel)
//   blocks 64..71   : embedding gather
//   blocks 72..1095 : GRU cell, one block per output element hh
// ---------------------------------------------------------------------------
__global__ void k_pre(const float* __restrict__ attn_w,
                      const float* __restrict__ v,
                      float* __restrict__ u,
                      const int* __restrict__ ids,
                      const float* __restrict__ emb,
                      float* __restrict__ out_emb,
                      const float* __restrict__ lctx,
                      const float* __restrict__ lhid,
                      const float* __restrict__ w_ih,
                      const float* __restrict__ w_hh,
                      const float* __restrict__ b_ih,
                      const float* __restrict__ b_hh,
                      float* __restrict__ o_hidden,
                      float* __restrict__ o_rnn) {
    __shared__ float red[16][16];
    __shared__ float lds[3][4][4];
    int bid = blockIdx.x;
    int t   = threadIdx.x;

    if (bid < 64) {
        // ---- u compute: h in [bid*16, bid*16+16) ----
        int kg = t >> 4;            // 0..15 (k-group of 64)
        int hi = t & 15;            // 0..15
        int h  = bid * 16 + hi;
        float acc = 0.f;
#pragma unroll 8
        for (int i = 0; i < 64; ++i) {
            int k = kg * 64 + i;
            acc += v[k] * attn_w[(long)k * (2 * H) + H + h];
        }
        red[kg][hi] = acc;
        __syncthreads();
        if (t < 16) {
            float s = 0.f;
#pragma unroll
            for (int g = 0; g < 16; ++g) s += red[g][t];
            u[bid * 16 + t] = s;
        }
        return;
    }
    if (bid < 72) {
        int idx = (bid - 64) * 256 + t;    // 0..2047
        int b = idx >> 10, h = idx & 1023;
        out_emb[idx] = emb[(long)ids[b] * H + h];
        return;
    }

    // ---- GRU ----
    int hh = bid - 72;            // 0..1023
    int kb = t * 8;               // x index base (0..2040)

    float4 x0a, x0b, x1a, x1b;
    if (kb < H) {
        const float* p0 = emb + (long)ids[0] * H + kb;
        const float* p1 = emb + (long)ids[1] * H + kb;
        x0a = *(const float4*)p0;       x0b = *(const float4*)(p0 + 4);
        x1a = *(const float4*)p1;       x1b = *(const float4*)(p1 + 4);
    } else {
        const float* p0 = lctx + (kb - H);
        const float* p1 = lctx + H + (kb - H);
        x0a = *(const float4*)p0;       x0b = *(const float4*)(p0 + 4);
        x1a = *(const float4*)p1;       x1b = *(const float4*)(p1 + 4);
    }
    int kb2 = t * 4;              // h index base (0..1020)
    float4 h0 = *(const float4*)(lhid + kb2);
    float4 h1 = *(const float4*)(lhid + H + kb2);

    for (int g = 0; g < 3; ++g) {
        const float* wi = w_ih + ((long)g * H + hh) * (2 * H) + kb;
        const float* wh = w_hh + ((long)g * H + hh) * H + kb2;
        float4 wa = *(const float4*)wi;
        float4 wb = *(const float4*)(wi + 4);
        float4 wc = *(const float4*)wh;
        float a0 = dot4(wa, x0a) + dot4(wb, x0b);
        float a1 = dot4(wa, x1a) + dot4(wb, x1b);
        float c0 = dot4(wc, h0);
        float c1 = dot4(wc, h1);
        for (int off = 32; off; off >>= 1) {
            a0 += __shfl_down(a0, off, 64);
            a1 += __shfl_down(a1, off, 64);
            c0 += __shfl_down(c0, off, 64);
            c1 += __shfl_down(c1, off, 64);
        }
        if ((t & 63) == 0) {
            int w = t >> 6;
            lds[g][w][0] = a0; lds[g][w][1] = a1;
            lds[g][w][2] = c0; lds[g][w][3] = c1;
        }
    }
    __syncthreads();
    if (t == 0) {
        float gx[3][2], gh[3][2];
        for (int g = 0; g < 3; ++g) {
            float s0 = 0, s1 = 0, s2 = 0, s3 = 0;
            for (int w = 0; w < 4; ++w) {
                s0 += lds[g][w][0]; s1 += lds[g][w][1];
                s2 += lds[g][w][2]; s3 += lds[g][w][3];
            }
            float bi = b_ih[g * H + hh], bh = b_hh[g * H + hh];
            gx[g][0] = s0 + bi; gx[g][1] = s1 + bi;
            gh[g][0] = s2 + bh; gh[g][1] = s3 + bh;
        }
        for (int b = 0; b < B2; ++b) {
            float r  = 1.f / (1.f + expf(-(gx[0][b] + gh[0][b])));
            float z  = 1.f / (1.f + expf(-(gx[1][b] + gh[1][b])));
            float n  = tanhf(gx[2][b] + r * gh[2][b]);
            float hp = lhid[b * H + hh];
            float hn = (1.f - z) * n + z * hp;
            o_hidden[b * H + hh] = hn;
            o_rnn[b * H + hh]    = hn;
        }
    }
}

// ---------------------------------------------------------------------------
// K2: energies[row] = enc[row,:] . u     (row = b*L + l, wave per row)
// grid 4096 x 256
// ---------------------------------------------------------------------------
__global__ void k_energy(const float* __restrict__ enc,
                         const float* __restrict__ u,
                         float* __restrict__ en) {
    int row  = (blockIdx.x << 2) + (threadIdx.x >> 6);
    int lane = threadIdx.x & 63;
    const float* e = enc + (long)row * H;
    float acc = 0.f;
#pragma unroll
    for (int c = 0; c < 4; ++c) {
        int k = c * 256 + lane * 4;
        float4 ev = *(const float4*)(e + k);
        float4 uv = *(const float4*)(u + k);
        acc += dot4(ev, uv);
    }
    for (int off = 32; off; off >>= 1) acc += __shfl_down(acc, off, 64);
    if (lane == 0) en[row] = acc;
}

// ---------------------------------------------------------------------------
// K3: context partials with inline softmax. block = (b, chunk of 32 l's).
// grid 512 x 256
// ---------------------------------------------------------------------------
__global__ void k_ctx(const float* __restrict__ enc,
                      const float* __restrict__ en,
                      float* __restrict__ part) {
    int b  = blockIdx.x >> 8;      // 0..1
    int lc = blockIdx.x & 255;     // 0..255
    int t  = threadIdx.x;
    const float* e_row = en + b * LEN;

    __shared__ float red[4];
    __shared__ float wlds[32];

    // block max over full energy row (L2-hot, 32KB)
    float m = -3.4e38f;
#pragma unroll 8
    for (int i = t; i < LEN; i += 256) m = fmaxf(m, e_row[i]);
    for (int off = 32; off; off >>= 1) m = fmaxf(m, __shfl_xor(m, off, 64));
    if ((t & 63) == 0) red[t >> 6] = m;
    __syncthreads();
    m = fmaxf(fmaxf(red[0], red[1]), fmaxf(red[2], red[3]));

    // block sum of exp
    float s = 0.f;
#pragma unroll 8
    for (int i = t; i < LEN; i += 256) s += expf(e_row[i] - m);
    for (int off = 32; off; off >>= 1) s += __shfl_xor(s, off, 64);
    __syncthreads();
    if ((t & 63) == 0) red[t >> 6] = s;
    __syncthreads();
    float inv = 1.f / (red[0] + red[1] + red[2] + red[3]);

    if (t < 32) wlds[t] = expf(e_row[lc * 32 + t] - m) * inv;
    __syncthreads();

    const float* e = enc + ((long)b * LEN + lc * 32) * H + t * 4;
    float4 acc = {0.f, 0.f, 0.f, 0.f};
#pragma unroll 8
    for (int i = 0; i < 32; ++i) {
        float w = wlds[i];
        float4 ev = *(const float4*)(e + (long)i * H);
        acc.x += w * ev.x; acc.y += w * ev.y; acc.z += w * ev.z; acc.w += w * ev.w;
    }
    *(float4*)(part + (long)blockIdx.x * H + t * 4) = acc;
}

// K4: reduce context partials -> context output. grid 8 x 256.
__global__ void k_ctx_red(const float* __restrict__ part,
                          float* __restrict__ out_ctx) {
    int idx = blockIdx.x * 256 + threadIdx.x;  // 0..2047 = b*H+h
    int b = idx >> 10, h = idx & 1023;
    float acc = 0.f;
#pragma unroll 8
    for (int lc = 0; lc < 256; ++lc) acc += part[(long)((b << 8) + lc) * H + h];
    out_ctx[idx] = acc;
}

// ---------------------------------------------------------------------------
// K5: output projection. Block stages cat (16KB) in LDS ONCE, then 4 waves
// each compute 4 rows (16 rows/block). No per-row global cat traffic.
// grid 3125 x 256
// ---------------------------------------------------------------------------
__global__ void __launch_bounds__(256)
k_out(const float* __restrict__ ow,
      const float* __restrict__ ob,
      const float* __restrict__ hnew,
      const float* __restrict__ ctx,
      float* __restrict__ out) {
    __shared__ float cat0[2 * H];
    __shared__ float cat1[2 * H];
    int t = threadIdx.x;
    {
        float4* c0 = (float4*)cat0;
        float4* c1 = (float4*)cat1;
#pragma unroll
        for (int r = 0; r < 2; ++r) {
            int idx = t + r * 256;         // 0..511 float4 index
            int k   = idx * 4;
            if (k < H) {
                c0[idx] = *(const float4*)(hnew + k);
                c1[idx] = *(const float4*)(hnew + H + k);
            } else {
                c0[idx] = *(const float4*)(ctx + (k - H));
                c1[idx] = *(const float4*)(ctx + H + (k - H));
            }
        }
    }
    __syncthreads();

    int lane = t & 63;
    int wv   = t >> 6;
    long rbase = (long)blockIdx.x * 16 + wv * 4;
    const float4* l0 = (const float4*)cat0;
    const float4* l1 = (const float4*)cat1;

    for (int r = 0; r < 4; ++r) {
        long row = rbase + r;
        const float4* w4 = (const float4*)(ow + row * (2 * H));
        float a0 = 0.f, a1 = 0.f;
#pragma unroll
        for (int j = 0; j < 8; ++j) {
            float4 w  = w4[lane + 64 * j];
            float4 v0 = l0[lane + 64 * j];
            float4 v1 = l1[lane + 64 * j];
            a0 += dot4(w, v0);
            a1 += dot4(w, v1);
        }
        for (int off = 32; off; off >>= 1) {
            a0 += __shfl_down(a0, off, 64);
            a1 += __shfl_down(a1, off, 64);
        }
        if (lane == 0) {
            float bb = ob[row];
            out[row]     = a0 + bb;
            out[V + row] = a1 + bb;
        }
    }
}

extern "C" void kernel_launch(void* const* d_in, const int* in_sizes, int n_in,
                              void* d_out, int out_size, void* d_ws, size_t ws_size,
                              hipStream_t stream) {
    const int*   ids    = (const int*)  d_in[0];
    const float* lctx   = (const float*)d_in[1];
    const float* lhid   = (const float*)d_in[2];
    const float* enc    = (const float*)d_in[3];
    const float* emb    = (const float*)d_in[4];
    const float* w_ih   = (const float*)d_in[5];
    const float* w_hh   = (const float*)d_in[6];
    const float* b_ih   = (const float*)d_in[7];
    const float* b_hh   = (const float*)d_in[8];
    const float* attn_w = (const float*)d_in[9];
    // d_in[10] = attn_b  (unused: shift-invariant under softmax)
    const float* v      = (const float*)d_in[11];
    const float* out_w  = (const float*)d_in[12];
    const float* out_b  = (const float*)d_in[13];

    float* out_f       = (float*)d_out;
    float* o_output    = out_f;             // (2,1,50000) = 100000
    float* o_context   = out_f + 100000;    // (2,1,1024)  = 2048
    float* o_hidden    = out_f + 102048;    // (1,2,1024)  = 2048
    float* o_embedded  = out_f + 104096;    // (2,1,1024)  = 2048
    float* o_rnn       = out_f + 106144;    // (2,1,1024)  = 2048

    float* ws   = (float*)d_ws;
    float* U    = ws;                  // 1024
    float* EN   = ws + 1024;           // 2*8192 = 16384
    float* PART = ws + 17408;          // 512*1024 = 524288 (~2.2 MB total)

    k_pre    <<<1096, 256, 0, stream>>>(attn_w, v, U, ids, emb, o_embedded,
                                        lctx, lhid, w_ih, w_hh, b_ih, b_hh,
                                        o_hidden, o_rnn);
    k_energy <<<4096, 256, 0, stream>>>(enc, U, EN);
    k_ctx    <<<512,  256, 0, stream>>>(enc, EN, PART);
    k_ctx_red<<<8,    256, 0, stream>>>(PART, o_context);
    k_out    <<<3125, 256, 0, stream>>>(out_w, out_b, o_hidden, o_context,
                                        o_output);
}

// Round 4
// 123.205 us; speedup vs baseline: 1.1091x; 1.1091x over previous
//
#include <hip/hip_runtime.h>

#define H 1024
#define LEN 8192
#define V 50000
#define NTILE 12500   // V / 4 rows per tile

__device__ __forceinline__ float dot4(float4 a, float4 b) {
    return a.x * b.x + a.y * b.y + a.z * b.z + a.w * b.w;
}

__device__ __forceinline__ void gld_lds16(const float* g, float* l) {
    __builtin_amdgcn_global_load_lds(
        (const __attribute__((address_space(1))) void*)g,
        (__attribute__((address_space(3))) void*)l, 16, 0, 0);
}

// ---------------------------------------------------------------------------
// K1: u[h] = sum_k v[k] * attn_w[k*2048 + 1024 + h].  grid 64 x 256.
// block handles 16 h's; 16 k-groups of 64 reduced through LDS.
// ---------------------------------------------------------------------------
__global__ void k_u(const float* __restrict__ attn_w,
                    const float* __restrict__ v,
                    float* __restrict__ u) {
    __shared__ float red[16][16];
    int bid = blockIdx.x;
    int t   = threadIdx.x;
    int kg  = t >> 4;            // 0..15
    int hi  = t & 15;            // 0..15
    int h   = bid * 16 + hi;
    float acc = 0.f;
#pragma unroll 8
    for (int i = 0; i < 64; ++i) {
        int k = kg * 64 + i;
        acc += v[k] * attn_w[(long)k * (2 * H) + H + h];
    }
    red[kg][hi] = acc;
    __syncthreads();
    if (t < 16) {
        float s = 0.f;
#pragma unroll
        for (int g = 0; g < 16; ++g) s += red[g][t];
        u[bid * 16 + t] = s;
    }
}

// ---------------------------------------------------------------------------
// K2: fused — blocks 0..4095: energies (wave per row);
//             blocks 4096..4103: embedding gather;
//             blocks 4104..5127: GRU cell (block per output element).
// ---------------------------------------------------------------------------
__global__ void k_big(const int* __restrict__ ids,
                      const float* __restrict__ emb,
                      const float* __restrict__ lctx,
                      const float* __restrict__ lhid,
                      const float* __restrict__ w_ih,
                      const float* __restrict__ w_hh,
                      const float* __restrict__ b_ih,
                      const float* __restrict__ b_hh,
                      const float* __restrict__ enc,
                      const float* __restrict__ u,
                      float* __restrict__ o_hidden,
                      float* __restrict__ o_rnn,
                      float* __restrict__ out_emb,
                      float* __restrict__ en) {
    __shared__ float lds[3][4][4];
    int bid = blockIdx.x;
    int t   = threadIdx.x;

    if (bid < 4096) {
        // ---- energies ----
        int row  = (bid << 2) + (t >> 6);     // 0..16383
        int lane = t & 63;
        const float* e = enc + (long)row * H;
        float acc = 0.f;
#pragma unroll
        for (int c = 0; c < 4; ++c) {
            int k = c * 256 + lane * 4;
            float4 ev = *(const float4*)(e + k);
            float4 uv = *(const float4*)(u + k);
            acc += dot4(ev, uv);
        }
        for (int off = 32; off; off >>= 1) acc += __shfl_down(acc, off, 64);
        if (lane == 0) en[row] = acc;
        return;
    }
    if (bid < 4104) {
        int idx = (bid - 4096) * 256 + t;     // 0..2047
        int b = idx >> 10, h = idx & 1023;
        out_emb[idx] = emb[(long)ids[b] * H + h];
        return;
    }

    // ---- GRU ----
    int hh = bid - 4104;          // 0..1023
    int kb = t * 8;               // x index base (0..2040)

    float4 x0a, x0b, x1a, x1b;
    if (kb < H) {
        const float* p0 = emb + (long)ids[0] * H + kb;
        const float* p1 = emb + (long)ids[1] * H + kb;
        x0a = *(const float4*)p0;       x0b = *(const float4*)(p0 + 4);
        x1a = *(const float4*)p1;       x1b = *(const float4*)(p1 + 4);
    } else {
        const float* p0 = lctx + (kb - H);
        const float* p1 = lctx + H + (kb - H);
        x0a = *(const float4*)p0;       x0b = *(const float4*)(p0 + 4);
        x1a = *(const float4*)p1;       x1b = *(const float4*)(p1 + 4);
    }
    int kb2 = t * 4;              // h index base (0..1020)
    float4 h0 = *(const float4*)(lhid + kb2);
    float4 h1 = *(const float4*)(lhid + H + kb2);

    for (int g = 0; g < 3; ++g) {
        const float* wi = w_ih + ((long)g * H + hh) * (2 * H) + kb;
        const float* wh = w_hh + ((long)g * H + hh) * H + kb2;
        float4 wa = *(const float4*)wi;
        float4 wb = *(const float4*)(wi + 4);
        float4 wc = *(const float4*)wh;
        float a0 = dot4(wa, x0a) + dot4(wb, x0b);
        float a1 = dot4(wa, x1a) + dot4(wb, x1b);
        float c0 = dot4(wc, h0);
        float c1 = dot4(wc, h1);
        for (int off = 32; off; off >>= 1) {
            a0 += __shfl_down(a0, off, 64);
            a1 += __shfl_down(a1, off, 64);
            c0 += __shfl_down(c0, off, 64);
            c1 += __shfl_down(c1, off, 64);
        }
        if ((t & 63) == 0) {
            int w = t >> 6;
            lds[g][w][0] = a0; lds[g][w][1] = a1;
            lds[g][w][2] = c0; lds[g][w][3] = c1;
        }
    }
    __syncthreads();
    if (t == 0) {
        float gx[3][2], gh[3][2];
        for (int g = 0; g < 3; ++g) {
            float s0 = 0, s1 = 0, s2 = 0, s3 = 0;
            for (int w = 0; w < 4; ++w) {
                s0 += lds[g][w][0]; s1 += lds[g][w][1];
                s2 += lds[g][w][2]; s3 += lds[g][w][3];
            }
            float bi = b_ih[g * H + hh], bh = b_hh[g * H + hh];
            gx[g][0] = s0 + bi; gx[g][1] = s1 + bi;
            gh[g][0] = s2 + bh; gh[g][1] = s3 + bh;
        }
        for (int b = 0; b < 2; ++b) {
            float r  = 1.f / (1.f + expf(-(gx[0][b] + gh[0][b])));
            float z  = 1.f / (1.f + expf(-(gx[1][b] + gh[1][b])));
            float n  = tanhf(gx[2][b] + r * gh[2][b]);
            float hp = lhid[b * H + hh];
            float hn = (1.f - z) * n + z * hp;
            o_hidden[b * H + hh] = hn;
            o_rnn[b * H + hh]    = hn;
        }
    }
}

// ---------------------------------------------------------------------------
// K3: context partials with inline softmax. block = (b, chunk of 32 l's).
// grid 512 x 256
// ---------------------------------------------------------------------------
__global__ void k_ctx(const float* __restrict__ enc,
                      const float* __restrict__ en,
                      float* __restrict__ part) {
    int b  = blockIdx.x >> 8;      // 0..1
    int lc = blockIdx.x & 255;     // 0..255
    int t  = threadIdx.x;
    const float* e_row = en + b * LEN;

    __shared__ float red[4];
    __shared__ float wlds[32];

    float m = -3.4e38f;
#pragma unroll 8
    for (int i = t; i < LEN; i += 256) m = fmaxf(m, e_row[i]);
    for (int off = 32; off; off >>= 1) m = fmaxf(m, __shfl_xor(m, off, 64));
    if ((t & 63) == 0) red[t >> 6] = m;
    __syncthreads();
    m = fmaxf(fmaxf(red[0], red[1]), fmaxf(red[2], red[3]));

    float s = 0.f;
#pragma unroll 8
    for (int i = t; i < LEN; i += 256) s += expf(e_row[i] - m);
    for (int off = 32; off; off >>= 1) s += __shfl_xor(s, off, 64);
    __syncthreads();
    if ((t & 63) == 0) red[t >> 6] = s;
    __syncthreads();
    float inv = 1.f / (red[0] + red[1] + red[2] + red[3]);

    if (t < 32) wlds[t] = expf(e_row[lc * 32 + t] - m) * inv;
    __syncthreads();

    const float* e = enc + ((long)b * LEN + lc * 32) * H + t * 4;
    float4 acc = {0.f, 0.f, 0.f, 0.f};
#pragma unroll 8
    for (int i = 0; i < 32; ++i) {
        float w = wlds[i];
        float4 ev = *(const float4*)(e + (long)i * H);
        acc.x += w * ev.x; acc.y += w * ev.y; acc.z += w * ev.z; acc.w += w * ev.w;
    }
    *(float4*)(part + (long)blockIdx.x * H + t * 4) = acc;
}

// ---------------------------------------------------------------------------
// K4: reduce 512 context partials -> context (2048). grid 64 x 256.
// block handles 32 output elements; 8 lc-groups of 32 reduced through LDS.
// ---------------------------------------------------------------------------
__global__ void k_ctx_red(const float* __restrict__ part,
                          float* __restrict__ out_ctx) {
    __shared__ float red[8][32];
    int t   = threadIdx.x;
    int il  = t & 31;               // 0..31
    int grp = t >> 5;               // 0..7
    int idx = blockIdx.x * 32 + il; // 0..2047 = b*H+h
    int b = idx >> 10, h = idx & 1023;
    const float* p = part + (long)(b << 8) * H + h;
    float acc = 0.f;
#pragma unroll 8
    for (int i = 0; i < 32; ++i) acc += p[(long)(grp * 32 + i) * H];
    red[grp][il] = acc;
    __syncthreads();
    if (t < 32) {
        float s = 0.f;
#pragma unroll
        for (int g = 0; g < 8; ++g) s += red[g][t];
        out_ctx[blockIdx.x * 32 + t] = s;
    }
}

// ---------------------------------------------------------------------------
// K5: output projection with global_load_lds double-buffered tile staging.
// Block: cat (16 KB) + 2 x 32 KB weight tiles in LDS (80 KB -> 2 blocks/CU).
// Each block loops tiles of 4 rows (grid-stride 512); wave per row; the
// stage of tile t+1 is issued BEFORE compute of tile t (one barrier/tile),
// so a full 32 KB stays in flight per block while computing.
// grid 512 x 256
// ---------------------------------------------------------------------------
__global__ void __launch_bounds__(256)
k_out(const float* __restrict__ ow,
      const float* __restrict__ ob,
      const float* __restrict__ hnew,
      const float* __restrict__ ctx,
      float* __restrict__ out) {
    __shared__ float cat[2][2 * H];       // 16 KB
    __shared__ float wt[2][4 * 2 * H];    // 64 KB
    int t    = threadIdx.x;
    int lane = t & 63;
    int wv   = t >> 6;

    // stage cat once
    {
        float4* c0 = (float4*)cat[0];
        float4* c1 = (float4*)cat[1];
#pragma unroll
        for (int r = 0; r < 2; ++r) {
            int idx = t + r * 256;         // float4 index 0..511
            int k   = idx * 4;
            if (k < H) {
                c0[idx] = *(const float4*)(hnew + k);
                c1[idx] = *(const float4*)(hnew + H + k);
            } else {
                c0[idx] = *(const float4*)(ctx + (k - H));
                c1[idx] = *(const float4*)(ctx + H + (k - H));
            }
        }
    }

    // stage first tile into wt[0]
    {
        const float* src = ow + (long)blockIdx.x * (4 * 2 * H);
#pragma unroll
        for (int i = 0; i < 8; ++i)
            gld_lds16(src + i * 1024 + t * 4, wt[0] + i * 1024 + t * 4);
    }
    __syncthreads();   // cat + tile0 ready

    const float4* c0 = (const float4*)cat[0];
    const float4* c1 = (const float4*)cat[1];
    int buf = 0;
    for (int T = blockIdx.x; T < NTILE; T += 512) {
        int Tn = T + 512;
        if (Tn < NTILE) {
            const float* src = ow + (long)Tn * (4 * 2 * H);
            float* dst = wt[buf ^ 1];
#pragma unroll
            for (int i = 0; i < 8; ++i)
                gld_lds16(src + i * 1024 + t * 4, dst + i * 1024 + t * 4);
        }
        // compute current tile: wave wv owns row T*4+wv (overlaps with stage)
        const float4* wr = (const float4*)(wt[buf] + wv * (2 * H));
        float a0 = 0.f, a1 = 0.f;
#pragma unroll
        for (int j = 0; j < 8; ++j) {
            float4 w = wr[lane + 64 * j];
            a0 += dot4(w, c0[lane + 64 * j]);
            a1 += dot4(w, c1[lane + 64 * j]);
        }
        for (int off = 32; off; off >>= 1) {
            a0 += __shfl_down(a0, off, 64);
            a1 += __shfl_down(a1, off, 64);
        }
        if (lane == 0) {
            long row = (long)T * 4 + wv;
            float bb = ob[row];
            out[row]     = a0 + bb;
            out[V + row] = a1 + bb;
        }
        __syncthreads();   // drains stage(Tn); all waves done reading wt[buf]
        buf ^= 1;
    }
}

extern "C" void kernel_launch(void* const* d_in, const int* in_sizes, int n_in,
                              void* d_out, int out_size, void* d_ws, size_t ws_size,
                              hipStream_t stream) {
    const int*   ids    = (const int*)  d_in[0];
    const float* lctx   = (const float*)d_in[1];
    const float* lhid   = (const float*)d_in[2];
    const float* enc    = (const float*)d_in[3];
    const float* emb    = (const float*)d_in[4];
    const float* w_ih   = (const float*)d_in[5];
    const float* w_hh   = (const float*)d_in[6];
    const float* b_ih   = (const float*)d_in[7];
    const float* b_hh   = (const float*)d_in[8];
    const float* attn_w = (const float*)d_in[9];
    // d_in[10] = attn_b  (unused: shift-invariant under softmax)
    const float* v      = (const float*)d_in[11];
    const float* out_w  = (const float*)d_in[12];
    const float* out_b  = (const float*)d_in[13];

    float* out_f       = (float*)d_out;
    float* o_output    = out_f;             // (2,1,50000) = 100000
    float* o_context   = out_f + 100000;    // (2,1,1024)  = 2048
    float* o_hidden    = out_f + 102048;    // (1,2,1024)  = 2048
    float* o_embedded  = out_f + 104096;    // (2,1,1024)  = 2048
    float* o_rnn       = out_f + 106144;    // (2,1,1024)  = 2048

    float* ws   = (float*)d_ws;
    float* U    = ws;                  // 1024
    float* EN   = ws + 1024;           // 2*8192 = 16384
    float* PART = ws + 17408;          // 512*1024 = 524288 (~2.2 MB total)

    k_u      <<<64,   256, 0, stream>>>(attn_w, v, U);
    k_big    <<<5128, 256, 0, stream>>>(ids, emb, lctx, lhid, w_ih, w_hh,
                                        b_ih, b_hh, enc, U,
                                        o_hidden, o_rnn, o_embedded, EN);
    k_ctx    <<<512,  256, 0, stream>>>(enc, EN, PART);
    k_ctx_red<<<64,   256, 0, stream>>>(PART, o_context);
    k_out    <<<512,  256, 0, stream>>>(out_w, out_b, o_hidden, o_context,
                                        o_output);
}

// Round 5
// 115.714 us; speedup vs baseline: 1.1809x; 1.0647x over previous
//
#include <hip/hip_runtime.h>

#define H 1024
#define LEN 8192
#define V 50000
#define NTILE 12500   // k_out: V/4 rows per tile
#define CHUNK 8
#define NCH (LEN / CHUNK)   // 1024 chunks per batch

__device__ __forceinline__ float dot4(float4 a, float4 b) {
    return a.x * b.x + a.y * b.y + a.z * b.z + a.w * b.w;
}

__device__ __forceinline__ void gld_lds16(const float* g, float* l) {
    __builtin_amdgcn_global_load_lds(
        (const __attribute__((address_space(1))) void*)g,
        (__attribute__((address_space(3))) void*)l, 16, 0, 0);
}

// ---------------------------------------------------------------------------
// K1: fused pre-work.
//   blocks 0..63    : u[h] = sum_k v[k]*attn_w[k*2048+1024+h]
//   blocks 64..71   : embedding gather
//   blocks 72..1095 : GRU cell, one block per output element hh
// ---------------------------------------------------------------------------
__global__ void k_pre(const float* __restrict__ attn_w,
                      const float* __restrict__ v,
                      float* __restrict__ u,
                      const int* __restrict__ ids,
                      const float* __restrict__ emb,
                      float* __restrict__ out_emb,
                      const float* __restrict__ lctx,
                      const float* __restrict__ lhid,
                      const float* __restrict__ w_ih,
                      const float* __restrict__ w_hh,
                      const float* __restrict__ b_ih,
                      const float* __restrict__ b_hh,
                      float* __restrict__ o_hidden,
                      float* __restrict__ o_rnn) {
    __shared__ float red[16][16];
    __shared__ float lds[3][4][4];
    int bid = blockIdx.x;
    int t   = threadIdx.x;

    if (bid < 64) {
        int kg = t >> 4;            // 0..15
        int hi = t & 15;            // 0..15
        int h  = bid * 16 + hi;
        float acc = 0.f;
#pragma unroll 8
        for (int i = 0; i < 64; ++i) {
            int k = kg * 64 + i;
            acc += v[k] * attn_w[(long)k * (2 * H) + H + h];
        }
        red[kg][hi] = acc;
        __syncthreads();
        if (t < 16) {
            float s = 0.f;
#pragma unroll
            for (int g = 0; g < 16; ++g) s += red[g][t];
            u[bid * 16 + t] = s;
        }
        return;
    }
    if (bid < 72) {
        int idx = (bid - 64) * 256 + t;    // 0..2047
        int b = idx >> 10, h = idx & 1023;
        out_emb[idx] = emb[(long)ids[b] * H + h];
        return;
    }

    // ---- GRU ----
    int hh = bid - 72;            // 0..1023
    int kb = t * 8;               // x index base (0..2040)

    float4 x0a, x0b, x1a, x1b;
    if (kb < H) {
        const float* p0 = emb + (long)ids[0] * H + kb;
        const float* p1 = emb + (long)ids[1] * H + kb;
        x0a = *(const float4*)p0;       x0b = *(const float4*)(p0 + 4);
        x1a = *(const float4*)p1;       x1b = *(const float4*)(p1 + 4);
    } else {
        const float* p0 = lctx + (kb - H);
        const float* p1 = lctx + H + (kb - H);
        x0a = *(const float4*)p0;       x0b = *(const float4*)(p0 + 4);
        x1a = *(const float4*)p1;       x1b = *(const float4*)(p1 + 4);
    }
    int kb2 = t * 4;              // h index base (0..1020)
    float4 h0 = *(const float4*)(lhid + kb2);
    float4 h1 = *(const float4*)(lhid + H + kb2);

    for (int g = 0; g < 3; ++g) {
        const float* wi = w_ih + ((long)g * H + hh) * (2 * H) + kb;
        const float* wh = w_hh + ((long)g * H + hh) * H + kb2;
        float4 wa = *(const float4*)wi;
        float4 wb = *(const float4*)(wi + 4);
        float4 wc = *(const float4*)wh;
        float a0 = dot4(wa, x0a) + dot4(wb, x0b);
        float a1 = dot4(wa, x1a) + dot4(wb, x1b);
        float c0 = dot4(wc, h0);
        float c1 = dot4(wc, h1);
        for (int off = 32; off; off >>= 1) {
            a0 += __shfl_down(a0, off, 64);
            a1 += __shfl_down(a1, off, 64);
            c0 += __shfl_down(c0, off, 64);
            c1 += __shfl_down(c1, off, 64);
        }
        if ((t & 63) == 0) {
            int w = t >> 6;
            lds[g][w][0] = a0; lds[g][w][1] = a1;
            lds[g][w][2] = c0; lds[g][w][3] = c1;
        }
    }
    __syncthreads();
    if (t == 0) {
        float gx[3][2], gh[3][2];
        for (int g = 0; g < 3; ++g) {
            float s0 = 0, s1 = 0, s2 = 0, s3 = 0;
            for (int w = 0; w < 4; ++w) {
                s0 += lds[g][w][0]; s1 += lds[g][w][1];
                s2 += lds[g][w][2]; s3 += lds[g][w][3];
            }
            float bi = b_ih[g * H + hh], bh = b_hh[g * H + hh];
            gx[g][0] = s0 + bi; gx[g][1] = s1 + bi;
            gh[g][0] = s2 + bh; gh[g][1] = s3 + bh;
        }
        for (int b = 0; b < 2; ++b) {
            float r  = 1.f / (1.f + expf(-(gx[0][b] + gh[0][b])));
            float z  = 1.f / (1.f + expf(-(gx[1][b] + gh[1][b])));
            float n  = tanhf(gx[2][b] + r * gh[2][b]);
            float hp = lhid[b * H + hh];
            float hn = (1.f - z) * n + z * hp;
            o_hidden[b * H + hh] = hn;
            o_rnn[b * H + hh]    = hn;
        }
    }
}

// ---------------------------------------------------------------------------
// K2: flash-style context partials. Block = (b, chunk of 8 l's).
// Stages 8 enc rows (32 KB) in LDS once, computes the 8 energies FROM LDS
// (no separate energy kernel, enc read from HBM exactly once), chunk-local
// softmax (m_c, s_c), unnormalized weighted sum. grid 2048 x 256.
// ---------------------------------------------------------------------------
__global__ void __launch_bounds__(256)
k_ctx(const float* __restrict__ enc,
      const float* __restrict__ u,
      float* __restrict__ pvec,
      float* __restrict__ marr,
      float* __restrict__ sarr) {
    __shared__ float erow[CHUNK * H];    // 32 KB
    __shared__ float elds[CHUNK];
    int t    = threadIdx.x;
    int lane = t & 63;
    int wv   = t >> 6;
    int b    = blockIdx.x >> 10;         // 0..1
    int ch   = blockIdx.x & 1023;        // 0..1023

    const float* src = enc + ((long)b * LEN + (long)ch * CHUNK) * H;
#pragma unroll
    for (int i = 0; i < CHUNK; ++i)
        gld_lds16(src + i * H + t * 4, erow + i * H + t * 4);

    // u fragment for this lane (L2-hot)
    float4 uf[4];
#pragma unroll
    for (int c = 0; c < 4; ++c)
        uf[c] = *(const float4*)(u + c * 256 + lane * 4);

    __syncthreads();   // staging drained

    // energies: wave wv computes rows 2wv, 2wv+1
#pragma unroll
    for (int rr = 0; rr < 2; ++rr) {
        int r = wv * 2 + rr;
        float acc = 0.f;
#pragma unroll
        for (int c = 0; c < 4; ++c) {
            float4 ev = *(const float4*)(erow + r * H + c * 256 + lane * 4);
            acc += dot4(ev, uf[c]);
        }
        for (int off = 32; off; off >>= 1) acc += __shfl_down(acc, off, 64);
        if (lane == 0) elds[r] = acc;
    }
    __syncthreads();

    float m = elds[0];
#pragma unroll
    for (int r = 1; r < CHUNK; ++r) m = fmaxf(m, elds[r]);
    float p[CHUNK];
    float s = 0.f;
#pragma unroll
    for (int r = 0; r < CHUNK; ++r) { p[r] = expf(elds[r] - m); s += p[r]; }

    float4 acc = {0.f, 0.f, 0.f, 0.f};
#pragma unroll
    for (int r = 0; r < CHUNK; ++r) {
        float4 ev = *(const float4*)(erow + r * H + t * 4);
        acc.x += p[r] * ev.x; acc.y += p[r] * ev.y;
        acc.z += p[r] * ev.z; acc.w += p[r] * ev.w;
    }
    *(float4*)(pvec + (long)blockIdx.x * H + t * 4) = acc;
    if (t == 0) { marr[blockIdx.x] = m; sarr[blockIdx.x] = s; }
}

// ---------------------------------------------------------------------------
// K3: flash combine. 64 blocks; block = (b, 32 h's).
// M = max m_c; scale_c = exp(m_c - M); ctx = sum scale_c*pvec_c / sum scale_c*s_c
// ---------------------------------------------------------------------------
__global__ void __launch_bounds__(256)
k_red(const float* __restrict__ pvec,
      const float* __restrict__ marr,
      const float* __restrict__ sarr,
      float* __restrict__ out_ctx) {
    __shared__ float scale[NCH];        // 4 KB
    __shared__ float red[8][32];
    int t  = threadIdx.x;
    int b  = blockIdx.x >> 5;           // 0..1
    int h0 = (blockIdx.x & 31) * 32;
    const float* mb = marr + b * NCH;
    const float* sb = sarr + b * NCH;

    // global max of chunk maxes
    float m = -3.4e38f;
    for (int i = t; i < NCH; i += 256) m = fmaxf(m, mb[i]);
    for (int off = 32; off; off >>= 1) m = fmaxf(m, __shfl_xor(m, off, 64));
    if ((t & 63) == 0) red[0][t >> 6] = m;
    __syncthreads();
    m = fmaxf(fmaxf(red[0][0], red[0][1]), fmaxf(red[0][2], red[0][3]));
    __syncthreads();

    // scales + denominator
    float d = 0.f;
    for (int i = t; i < NCH; i += 256) {
        float sc = expf(mb[i] - m);
        scale[i] = sc;
        d += sc * sb[i];
    }
    for (int off = 32; off; off >>= 1) d += __shfl_xor(d, off, 64);
    if ((t & 63) == 0) red[0][t >> 6] = d;
    __syncthreads();
    float inv = 1.f / (red[0][0] + red[0][1] + red[0][2] + red[0][3]);
    __syncthreads();

    // weighted sum over 1024 chunks; 8 groups of 32 threads
    int grp = t >> 5, il = t & 31;
    const float* pv = pvec + (long)b * NCH * H + (h0 + il);
    float acc = 0.f;
#pragma unroll 4
    for (int c = grp * 128; c < grp * 128 + 128; ++c)
        acc += scale[c] * pv[(long)c * H];
    red[grp][il] = acc;
    __syncthreads();
    if (t < 32) {
        float ssum = 0.f;
#pragma unroll
        for (int g = 0; g < 8; ++g) ssum += red[g][t];
        out_ctx[b * H + h0 + t] = ssum * inv;
    }
}

// ---------------------------------------------------------------------------
// K4: output projection with global_load_lds double-buffered tile staging.
// (unchanged from round 4 — it measured as an improvement)
// ---------------------------------------------------------------------------
__global__ void __launch_bounds__(256)
k_out(const float* __restrict__ ow,
      const float* __restrict__ ob,
      const float* __restrict__ hnew,
      const float* __restrict__ ctx,
      float* __restrict__ out) {
    __shared__ float cat[2][2 * H];       // 16 KB
    __shared__ float wt[2][4 * 2 * H];    // 64 KB
    int t    = threadIdx.x;
    int lane = t & 63;
    int wv   = t >> 6;

    {
        float4* c0 = (float4*)cat[0];
        float4* c1 = (float4*)cat[1];
#pragma unroll
        for (int r = 0; r < 2; ++r) {
            int idx = t + r * 256;
            int k   = idx * 4;
            if (k < H) {
                c0[idx] = *(const float4*)(hnew + k);
                c1[idx] = *(const float4*)(hnew + H + k);
            } else {
                c0[idx] = *(const float4*)(ctx + (k - H));
                c1[idx] = *(const float4*)(ctx + H + (k - H));
            }
        }
    }
    {
        const float* src = ow + (long)blockIdx.x * (4 * 2 * H);
#pragma unroll
        for (int i = 0; i < 8; ++i)
            gld_lds16(src + i * 1024 + t * 4, wt[0] + i * 1024 + t * 4);
    }
    __syncthreads();

    const float4* c0 = (const float4*)cat[0];
    const float4* c1 = (const float4*)cat[1];
    int buf = 0;
    for (int T = blockIdx.x; T < NTILE; T += 512) {
        int Tn = T + 512;
        if (Tn < NTILE) {
            const float* src = ow + (long)Tn * (4 * 2 * H);
            float* dst = wt[buf ^ 1];
#pragma unroll
            for (int i = 0; i < 8; ++i)
                gld_lds16(src + i * 1024 + t * 4, dst + i * 1024 + t * 4);
        }
        const float4* wr = (const float4*)(wt[buf] + wv * (2 * H));
        float a0 = 0.f, a1 = 0.f;
#pragma unroll
        for (int j = 0; j < 8; ++j) {
            float4 w = wr[lane + 64 * j];
            a0 += dot4(w, c0[lane + 64 * j]);
            a1 += dot4(w, c1[lane + 64 * j]);
        }
        for (int off = 32; off; off >>= 1) {
            a0 += __shfl_down(a0, off, 64);
            a1 += __shfl_down(a1, off, 64);
        }
        if (lane == 0) {
            long row = (long)T * 4 + wv;
            float bb = ob[row];
            out[row]     = a0 + bb;
            out[V + row] = a1 + bb;
        }
        __syncthreads();
        buf ^= 1;
    }
}

extern "C" void kernel_launch(void* const* d_in, const int* in_sizes, int n_in,
                              void* d_out, int out_size, void* d_ws, size_t ws_size,
                              hipStream_t stream) {
    const int*   ids    = (const int*)  d_in[0];
    const float* lctx   = (const float*)d_in[1];
    const float* lhid   = (const float*)d_in[2];
    const float* enc    = (const float*)d_in[3];
    const float* emb    = (const float*)d_in[4];
    const float* w_ih   = (const float*)d_in[5];
    const float* w_hh   = (const float*)d_in[6];
    const float* b_ih   = (const float*)d_in[7];
    const float* b_hh   = (const float*)d_in[8];
    const float* attn_w = (const float*)d_in[9];
    // d_in[10] = attn_b  (unused: shift-invariant under softmax)
    const float* v      = (const float*)d_in[11];
    const float* out_w  = (const float*)d_in[12];
    const float* out_b  = (const float*)d_in[13];

    float* out_f       = (float*)d_out;
    float* o_output    = out_f;             // (2,1,50000) = 100000
    float* o_context   = out_f + 100000;    // (2,1,1024)  = 2048
    float* o_hidden    = out_f + 102048;    // (1,2,1024)  = 2048
    float* o_embedded  = out_f + 104096;    // (2,1,1024)  = 2048
    float* o_rnn       = out_f + 106144;    // (2,1,1024)  = 2048

    float* ws   = (float*)d_ws;
    float* U    = ws;                    // 1024
    float* MARR = ws + 1024;             // 2048
    float* SARR = ws + 3072;             // 2048
    float* PVEC = ws + 5120;             // 2048*1024 = 2097152 (~8.4 MB total)

    k_pre<<<1096, 256, 0, stream>>>(attn_w, v, U, ids, emb, o_embedded,
                                    lctx, lhid, w_ih, w_hh, b_ih, b_hh,
                                    o_hidden, o_rnn);
    k_ctx<<<2048, 256, 0, stream>>>(enc, U, PVEC, MARR, SARR);
    k_red<<<64,   256, 0, stream>>>(PVEC, MARR, SARR, o_context);
    k_out<<<512,  256, 0, stream>>>(out_w, out_b, o_hidden, o_context,
                                    o_output);
}